// Round 1
// baseline (1186.604 us; speedup 1.0000x reference)
//
#include <hip/hip_runtime.h>

// GCN: 4x [h=(x*ns)@W ; agg=segment_sum(h[src],dst) ; out=agg*nd+b (+relu)]
// N=100000 nodes, E=1.6M edges, feats 128->64->64->64->40, fp32.

constexpr int BLK = 256;

__global__ void zero_int(int* p, int n) {
  int i = blockIdx.x * blockDim.x + threadIdx.x;
  if (i < n) p[i] = 0;
}

__global__ void count_deg(const int* __restrict__ src, const int* __restrict__ dst,
                          int* deg_out, int* deg_in, int e) {
  int i = blockIdx.x * blockDim.x + threadIdx.x;
  if (i < e) {
    atomicAdd(&deg_out[src[i]], 1);
    atomicAdd(&deg_in[dst[i]], 1);
  }
}

__global__ void norms_k(const int* __restrict__ deg_out, const int* __restrict__ deg_in,
                        float* ns, float* nd, int n) {
  int i = blockIdx.x * blockDim.x + threadIdx.x;
  if (i < n) {
    int od = deg_out[i], idg = deg_in[i];
    ns[i] = od > 0 ? rsqrtf((float)od) : 0.f;
    nd[i] = idg > 0 ? rsqrtf((float)idg) : 0.f;
  }
}

// ---- two-level exclusive scan of deg_in (chunk = 1024 = 256 thr x 4) ----
__global__ void scan_bsum(const int* __restrict__ deg, int* bsum, int n) {
  int tid = threadIdx.x;
  int base = blockIdx.x * 1024 + tid * 4;
  int s = 0;
  #pragma unroll
  for (int j = 0; j < 4; ++j) { int i = base + j; if (i < n) s += deg[i]; }
  int lane = tid & 63, wid = tid >> 6;
  #pragma unroll
  for (int off = 32; off > 0; off >>= 1) s += __shfl_down(s, off, 64);
  __shared__ int wtot[4];
  if (lane == 0) wtot[wid] = s;
  __syncthreads();
  if (tid == 0) bsum[blockIdx.x] = wtot[0] + wtot[1] + wtot[2] + wtot[3];
}

__global__ void scan_small(int* bsum, int nb, int* row_ptr, int n) {
  if (threadIdx.x == 0 && blockIdx.x == 0) {
    int acc = 0;
    for (int i = 0; i < nb; ++i) { int v = bsum[i]; bsum[i] = acc; acc += v; }
    row_ptr[n] = acc;
  }
}

__global__ void scan_chunks(const int* __restrict__ deg, const int* __restrict__ bsum,
                            int* row_ptr, int* cursor, int n) {
  int tid = threadIdx.x;
  int base = blockIdx.x * 1024 + tid * 4;
  int v0 = 0, v1 = 0, v2 = 0, v3 = 0;
  if (base + 0 < n) v0 = deg[base + 0];
  if (base + 1 < n) v1 = deg[base + 1];
  if (base + 2 < n) v2 = deg[base + 2];
  if (base + 3 < n) v3 = deg[base + 3];
  int s = v0 + v1 + v2 + v3;
  int lane = tid & 63, wid = tid >> 6;
  int incl = s;
  #pragma unroll
  for (int off = 1; off < 64; off <<= 1) {
    int t = __shfl_up(incl, off, 64);
    if (lane >= off) incl += t;
  }
  __shared__ int wtot[4];
  if (lane == 63) wtot[wid] = incl;
  __syncthreads();
  int woff = 0;
  for (int w = 0; w < wid; ++w) woff += wtot[w];
  int run = bsum[blockIdx.x] + woff + (incl - s);
  if (base + 0 < n) { row_ptr[base + 0] = run; cursor[base + 0] = run; } run += v0;
  if (base + 1 < n) { row_ptr[base + 1] = run; cursor[base + 1] = run; } run += v1;
  if (base + 2 < n) { row_ptr[base + 2] = run; cursor[base + 2] = run; } run += v2;
  if (base + 3 < n) { row_ptr[base + 3] = run; cursor[base + 3] = run; }
}

__global__ void fill_csr(const int* __restrict__ src, const int* __restrict__ dst,
                         int* cursor, int* esrc, int e) {
  int i = blockIdx.x * blockDim.x + threadIdx.x;
  if (i < e) {
    int pos = atomicAdd(&cursor[dst[i]], 1);
    esrc[pos] = src[i];
  }
}

// ---- h = (x*ns) @ W ; one wave per node, lane = output feature ----
template <int K, int F>
__global__ void gemm_ns(const float* __restrict__ x, const float* __restrict__ W,
                        const float* __restrict__ ns, float* __restrict__ h, int n) {
  __shared__ float sW[K * F];
  for (int i = threadIdx.x; i < K * F; i += BLK) sW[i] = W[i];
  __syncthreads();
  int f = threadIdx.x & 63;
  int node = blockIdx.x * 4 + (threadIdx.x >> 6);
  if (node >= n) return;
  if (f < F) {
    const float4* x4 = (const float4*)(x + (size_t)node * K);
    float acc = 0.f;
    #pragma unroll
    for (int k4 = 0; k4 < K / 4; ++k4) {
      float4 xv = x4[k4];
      int kb = k4 * 4;
      acc = fmaf(xv.x, sW[(kb + 0) * F + f], acc);
      acc = fmaf(xv.y, sW[(kb + 1) * F + f], acc);
      acc = fmaf(xv.z, sW[(kb + 2) * F + f], acc);
      acc = fmaf(xv.w, sW[(kb + 3) * F + f], acc);
    }
    h[(size_t)node * F + f] = acc * ns[node];
  }
}

// ---- agg[n] = sum_{e: dst=n} h[src_e] ; out = agg*nd + b (+relu) ----
template <int F, bool RELU>
__global__ void agg_csr(const float* __restrict__ h, const int* __restrict__ row_ptr,
                        const int* __restrict__ esrc, const float* __restrict__ nd,
                        const float* __restrict__ b, float* __restrict__ out, int n) {
  int f = threadIdx.x & 63;
  int node = blockIdx.x * 4 + (threadIdx.x >> 6);
  if (node >= n) return;
  int beg = row_ptr[node], end = row_ptr[node + 1];
  if (f < F) {
    float acc = 0.f;
    for (int k = beg; k < end; ++k) {
      int s = esrc[k];
      acc += h[(size_t)s * F + f];
    }
    float o = acc * nd[node] + b[f];
    if (RELU) o = fmaxf(o, 0.f);
    out[(size_t)node * F + f] = o;
  }
}

extern "C" void kernel_launch(void* const* d_in, const int* in_sizes, int n_in,
                              void* d_out, int out_size, void* d_ws, size_t ws_size,
                              hipStream_t stream) {
  const float* features = (const float*)d_in[0];
  const int* src = (const int*)d_in[1];
  const int* dst = (const int*)d_in[2];
  const float* W0 = (const float*)d_in[3];
  const float* b0 = (const float*)d_in[4];
  const float* W1 = (const float*)d_in[5];
  const float* b1 = (const float*)d_in[6];
  const float* W2 = (const float*)d_in[7];
  const float* b2 = (const float*)d_in[8];
  const float* W3 = (const float*)d_in[9];
  const float* b3 = (const float*)d_in[10];

  const int n = in_sizes[0] / 128;  // 100000
  const int e = in_sizes[1];        // 1600000

  // workspace carve-up (256B aligned)
  char* p = (char*)d_ws;
  auto alloc = [&](size_t bytes) {
    void* q = (void*)p;
    p += (bytes + 255) & ~(size_t)255;
    return q;
  };
  int* deg = (int*)alloc((size_t)2 * n * 4);       // deg_out = deg, deg_in = deg+n
  float* ns = (float*)alloc((size_t)n * 4);
  float* nd = (float*)alloc((size_t)n * 4);
  int* row_ptr = (int*)alloc((size_t)(n + 1) * 4);
  int* cursor = (int*)alloc((size_t)n * 4);
  int* bsum = (int*)alloc(4096);
  int* esrc = (int*)alloc((size_t)e * 4);
  float* h = (float*)alloc((size_t)n * 64 * 4);
  float* xb = (float*)alloc((size_t)n * 64 * 4);

  int* deg_out = deg;
  int* deg_in = deg + n;
  const int nblk_scan = (n + 1023) / 1024;  // 98

  zero_int<<<(2 * n + BLK - 1) / BLK, BLK, 0, stream>>>(deg, 2 * n);
  count_deg<<<(e + BLK - 1) / BLK, BLK, 0, stream>>>(src, dst, deg_out, deg_in, e);
  norms_k<<<(n + BLK - 1) / BLK, BLK, 0, stream>>>(deg_out, deg_in, ns, nd, n);
  scan_bsum<<<nblk_scan, BLK, 0, stream>>>(deg_in, bsum, n);
  scan_small<<<1, 64, 0, stream>>>(bsum, nblk_scan, row_ptr, n);
  scan_chunks<<<nblk_scan, BLK, 0, stream>>>(deg_in, bsum, row_ptr, cursor, n);
  fill_csr<<<(e + BLK - 1) / BLK, BLK, 0, stream>>>(src, dst, cursor, esrc, e);

  const int gnode = (n + 3) / 4;  // 4 nodes (waves) per block

  // layer 0: 128 -> 64, relu
  gemm_ns<128, 64><<<gnode, BLK, 0, stream>>>(features, W0, ns, h, n);
  agg_csr<64, true><<<gnode, BLK, 0, stream>>>(h, row_ptr, esrc, nd, b0, xb, n);
  // layer 1: 64 -> 64, relu
  gemm_ns<64, 64><<<gnode, BLK, 0, stream>>>(xb, W1, ns, h, n);
  agg_csr<64, true><<<gnode, BLK, 0, stream>>>(h, row_ptr, esrc, nd, b1, xb, n);
  // layer 2: 64 -> 64, relu
  gemm_ns<64, 64><<<gnode, BLK, 0, stream>>>(xb, W2, ns, h, n);
  agg_csr<64, true><<<gnode, BLK, 0, stream>>>(h, row_ptr, esrc, nd, b2, xb, n);
  // layer 3: 64 -> 40, no relu
  gemm_ns<64, 40><<<gnode, BLK, 0, stream>>>(xb, W3, ns, h, n);
  agg_csr<40, false><<<gnode, BLK, 0, stream>>>(h, row_ptr, esrc, nd, b3, (float*)d_out, n);
}

// Round 2
// 829.515 us; speedup vs baseline: 1.4305x; 1.4305x over previous
//
#include <hip/hip_runtime.h>

// GCN: 4x [h=(x*ns)@W ; agg=segment_sum(h[src],dst) ; out=agg*nd+b (+relu)]
// N=100000 nodes, E=1.6M edges, feats 128->64->64->64->40, fp32.
// R2: agg processes 4 edges/wave-iteration (16 lanes x float4 per edge row),
//     shfl_xor cross-group reduction. Layer-3 h rows padded to stride 64.

constexpr int BLK = 256;

__global__ void zero_int(int* p, int n) {
  int i = blockIdx.x * blockDim.x + threadIdx.x;
  if (i < n) p[i] = 0;
}

__global__ void count_deg(const int* __restrict__ src, const int* __restrict__ dst,
                          int* deg_out, int* deg_in, int e) {
  int i = blockIdx.x * blockDim.x + threadIdx.x;
  if (i < e) {
    atomicAdd(&deg_out[src[i]], 1);
    atomicAdd(&deg_in[dst[i]], 1);
  }
}

__global__ void norms_k(const int* __restrict__ deg_out, const int* __restrict__ deg_in,
                        float* ns, float* nd, int n) {
  int i = blockIdx.x * blockDim.x + threadIdx.x;
  if (i < n) {
    int od = deg_out[i], idg = deg_in[i];
    ns[i] = od > 0 ? rsqrtf((float)od) : 0.f;
    nd[i] = idg > 0 ? rsqrtf((float)idg) : 0.f;
  }
}

// ---- two-level exclusive scan of deg_in (chunk = 1024 = 256 thr x 4) ----
__global__ void scan_bsum(const int* __restrict__ deg, int* bsum, int n) {
  int tid = threadIdx.x;
  int base = blockIdx.x * 1024 + tid * 4;
  int s = 0;
  #pragma unroll
  for (int j = 0; j < 4; ++j) { int i = base + j; if (i < n) s += deg[i]; }
  int lane = tid & 63, wid = tid >> 6;
  #pragma unroll
  for (int off = 32; off > 0; off >>= 1) s += __shfl_down(s, off, 64);
  __shared__ int wtot[4];
  if (lane == 0) wtot[wid] = s;
  __syncthreads();
  if (tid == 0) bsum[blockIdx.x] = wtot[0] + wtot[1] + wtot[2] + wtot[3];
}

__global__ void scan_small(int* bsum, int nb, int* row_ptr, int n) {
  if (threadIdx.x == 0 && blockIdx.x == 0) {
    int acc = 0;
    for (int i = 0; i < nb; ++i) { int v = bsum[i]; bsum[i] = acc; acc += v; }
    row_ptr[n] = acc;
  }
}

__global__ void scan_chunks(const int* __restrict__ deg, const int* __restrict__ bsum,
                            int* row_ptr, int* cursor, int n) {
  int tid = threadIdx.x;
  int base = blockIdx.x * 1024 + tid * 4;
  int v0 = 0, v1 = 0, v2 = 0, v3 = 0;
  if (base + 0 < n) v0 = deg[base + 0];
  if (base + 1 < n) v1 = deg[base + 1];
  if (base + 2 < n) v2 = deg[base + 2];
  if (base + 3 < n) v3 = deg[base + 3];
  int s = v0 + v1 + v2 + v3;
  int lane = tid & 63, wid = tid >> 6;
  int incl = s;
  #pragma unroll
  for (int off = 1; off < 64; off <<= 1) {
    int t = __shfl_up(incl, off, 64);
    if (lane >= off) incl += t;
  }
  __shared__ int wtot[4];
  if (lane == 63) wtot[wid] = incl;
  __syncthreads();
  int woff = 0;
  for (int w = 0; w < wid; ++w) woff += wtot[w];
  int run = bsum[blockIdx.x] + woff + (incl - s);
  if (base + 0 < n) { row_ptr[base + 0] = run; cursor[base + 0] = run; } run += v0;
  if (base + 1 < n) { row_ptr[base + 1] = run; cursor[base + 1] = run; } run += v1;
  if (base + 2 < n) { row_ptr[base + 2] = run; cursor[base + 2] = run; } run += v2;
  if (base + 3 < n) { row_ptr[base + 3] = run; cursor[base + 3] = run; }
}

__global__ void fill_csr(const int* __restrict__ src, const int* __restrict__ dst,
                         int* cursor, int* esrc, int e) {
  int i = blockIdx.x * blockDim.x + threadIdx.x;
  if (i < e) {
    int pos = atomicAdd(&cursor[dst[i]], 1);
    esrc[pos] = src[i];
  }
}

// ---- h = (x*ns) @ W ; one wave per node, lane = output feature ----
// STRIDE-wide h rows; lanes f in [F, STRIDE) write 0 (padding for agg4).
template <int K, int F, int STRIDE>
__global__ void gemm_ns(const float* __restrict__ x, const float* __restrict__ W,
                        const float* __restrict__ ns, float* __restrict__ h, int n) {
  __shared__ float sW[K * F];
  for (int i = threadIdx.x; i < K * F; i += BLK) sW[i] = W[i];
  __syncthreads();
  int f = threadIdx.x & 63;
  int node = blockIdx.x * 4 + (threadIdx.x >> 6);
  if (node >= n) return;
  int fc = f < F ? f : 0;
  const float4* x4 = (const float4*)(x + (size_t)node * K);
  float acc = 0.f;
  #pragma unroll
  for (int k4 = 0; k4 < K / 4; ++k4) {
    float4 xv = x4[k4];
    int kb = k4 * 4;
    acc = fmaf(xv.x, sW[(kb + 0) * F + fc], acc);
    acc = fmaf(xv.y, sW[(kb + 1) * F + fc], acc);
    acc = fmaf(xv.z, sW[(kb + 2) * F + fc], acc);
    acc = fmaf(xv.w, sW[(kb + 3) * F + fc], acc);
  }
  float v = (f < F) ? acc * ns[node] : 0.f;
  if (f < STRIDE) h[(size_t)node * STRIDE + f] = v;
}

// ---- agg: 4 edges per wave-iteration; h rows are stride-64 fp32.
// group g = lane>>4 handles edge k+g; 16 lanes x float4 = 256B row.
// After loop: shfl_xor(16), shfl_xor(32) reduce across groups; lanes 0-15
// hold final float4; store OUTF floats (OUTF/4 lanes active).
template <bool RELU, int OUTF>
__global__ void agg4(const float* __restrict__ h, const int* __restrict__ row_ptr,
                     const int* __restrict__ esrc, const float* __restrict__ nd,
                     const float* __restrict__ b, float* __restrict__ out, int n) {
  int tid = threadIdx.x;
  int node = blockIdx.x * 4 + (tid >> 6);
  if (node >= n) return;
  int lane = tid & 63;
  int g = lane >> 4;
  int fl = lane & 15;
  int beg = row_ptr[node], end = row_ptr[node + 1];
  float ax = 0.f, ay = 0.f, az = 0.f, aw = 0.f;
  #pragma unroll 2
  for (int k = beg + g; k < end; k += 4) {
    int s = esrc[k];
    float4 v = *(const float4*)(h + (size_t)s * 64 + fl * 4);
    ax += v.x; ay += v.y; az += v.z; aw += v.w;
  }
  ax += __shfl_xor(ax, 16, 64); ay += __shfl_xor(ay, 16, 64);
  az += __shfl_xor(az, 16, 64); aw += __shfl_xor(aw, 16, 64);
  ax += __shfl_xor(ax, 32, 64); ay += __shfl_xor(ay, 32, 64);
  az += __shfl_xor(az, 32, 64); aw += __shfl_xor(aw, 32, 64);
  if (lane < OUTF / 4) {
    float ndv = nd[node];
    float4 bv = ((const float4*)b)[fl];
    float4 o;
    o.x = ax * ndv + bv.x;
    o.y = ay * ndv + bv.y;
    o.z = az * ndv + bv.z;
    o.w = aw * ndv + bv.w;
    if (RELU) {
      o.x = fmaxf(o.x, 0.f); o.y = fmaxf(o.y, 0.f);
      o.z = fmaxf(o.z, 0.f); o.w = fmaxf(o.w, 0.f);
    }
    *(float4*)(out + (size_t)node * OUTF + fl * 4) = o;
  }
}

extern "C" void kernel_launch(void* const* d_in, const int* in_sizes, int n_in,
                              void* d_out, int out_size, void* d_ws, size_t ws_size,
                              hipStream_t stream) {
  const float* features = (const float*)d_in[0];
  const int* src = (const int*)d_in[1];
  const int* dst = (const int*)d_in[2];
  const float* W0 = (const float*)d_in[3];
  const float* b0 = (const float*)d_in[4];
  const float* W1 = (const float*)d_in[5];
  const float* b1 = (const float*)d_in[6];
  const float* W2 = (const float*)d_in[7];
  const float* b2 = (const float*)d_in[8];
  const float* W3 = (const float*)d_in[9];
  const float* b3 = (const float*)d_in[10];

  const int n = in_sizes[0] / 128;  // 100000
  const int e = in_sizes[1];        // 1600000

  char* p = (char*)d_ws;
  auto alloc = [&](size_t bytes) {
    void* q = (void*)p;
    p += (bytes + 255) & ~(size_t)255;
    return q;
  };
  int* deg = (int*)alloc((size_t)2 * n * 4);
  float* ns = (float*)alloc((size_t)n * 4);
  float* nd = (float*)alloc((size_t)n * 4);
  int* row_ptr = (int*)alloc((size_t)(n + 1) * 4);
  int* cursor = (int*)alloc((size_t)n * 4);
  int* bsum = (int*)alloc(4096);
  int* esrc = (int*)alloc((size_t)e * 4);
  float* h = (float*)alloc((size_t)n * 64 * 4);
  float* xb = (float*)alloc((size_t)n * 64 * 4);

  int* deg_out = deg;
  int* deg_in = deg + n;
  const int nblk_scan = (n + 1023) / 1024;

  zero_int<<<(2 * n + BLK - 1) / BLK, BLK, 0, stream>>>(deg, 2 * n);
  count_deg<<<(e + BLK - 1) / BLK, BLK, 0, stream>>>(src, dst, deg_out, deg_in, e);
  norms_k<<<(n + BLK - 1) / BLK, BLK, 0, stream>>>(deg_out, deg_in, ns, nd, n);
  scan_bsum<<<nblk_scan, BLK, 0, stream>>>(deg_in, bsum, n);
  scan_small<<<1, 64, 0, stream>>>(bsum, nblk_scan, row_ptr, n);
  scan_chunks<<<nblk_scan, BLK, 0, stream>>>(deg_in, bsum, row_ptr, cursor, n);
  fill_csr<<<(e + BLK - 1) / BLK, BLK, 0, stream>>>(src, dst, cursor, esrc, e);

  const int gnode = (n + 3) / 4;

  // layer 0: 128 -> 64, relu
  gemm_ns<128, 64, 64><<<gnode, BLK, 0, stream>>>(features, W0, ns, h, n);
  agg4<true, 64><<<gnode, BLK, 0, stream>>>(h, row_ptr, esrc, nd, b0, xb, n);
  // layer 1: 64 -> 64, relu
  gemm_ns<64, 64, 64><<<gnode, BLK, 0, stream>>>(xb, W1, ns, h, n);
  agg4<true, 64><<<gnode, BLK, 0, stream>>>(h, row_ptr, esrc, nd, b1, xb, n);
  // layer 2: 64 -> 64, relu
  gemm_ns<64, 64, 64><<<gnode, BLK, 0, stream>>>(xb, W2, ns, h, n);
  agg4<true, 64><<<gnode, BLK, 0, stream>>>(h, row_ptr, esrc, nd, b2, xb, n);
  // layer 3: 64 -> 40, no relu (h padded to stride 64)
  gemm_ns<64, 40, 64><<<gnode, BLK, 0, stream>>>(xb, W3, ns, h, n);
  agg4<false, 40><<<gnode, BLK, 0, stream>>>(h, row_ptr, esrc, nd, b3, (float*)d_out, n);
}

// Round 3
// 728.804 us; speedup vs baseline: 1.6282x; 1.1382x over previous
//
#include <hip/hip_runtime.h>

// GCN: 4x [h=(x*ns)@W ; agg=segment_sum(h[src],dst) ; out=agg*nd+b (+relu)]
// N=100000 nodes, E=1.6M edges, feats 128->64->64->64->40, fp32.
// R3: gemm4 = 4 nodes/wave, chunk-transposed W in LDS (ds_read_b128),
//     scalarized x loads via readfirstlane; agg4 unroll 4; int4 edge prep.

constexpr int BLK = 256;

__global__ void zero_int(int* p, int n) {
  int i = blockIdx.x * blockDim.x + threadIdx.x;
  if (i < n) p[i] = 0;
}

__global__ void count_deg4(const int* __restrict__ src, const int* __restrict__ dst,
                           int* deg_out, int* deg_in, int e) {
  int i = (blockIdx.x * blockDim.x + threadIdx.x) * 4;
  if (i + 3 < e) {
    int4 s = *(const int4*)(src + i);
    int4 d = *(const int4*)(dst + i);
    atomicAdd(&deg_out[s.x], 1); atomicAdd(&deg_out[s.y], 1);
    atomicAdd(&deg_out[s.z], 1); atomicAdd(&deg_out[s.w], 1);
    atomicAdd(&deg_in[d.x], 1); atomicAdd(&deg_in[d.y], 1);
    atomicAdd(&deg_in[d.z], 1); atomicAdd(&deg_in[d.w], 1);
  } else {
    for (; i < e; ++i) {
      atomicAdd(&deg_out[src[i]], 1);
      atomicAdd(&deg_in[dst[i]], 1);
    }
  }
}

__global__ void norms_k(const int* __restrict__ deg_out, const int* __restrict__ deg_in,
                        float* ns, float* nd, int n) {
  int i = blockIdx.x * blockDim.x + threadIdx.x;
  if (i < n) {
    int od = deg_out[i], idg = deg_in[i];
    ns[i] = od > 0 ? rsqrtf((float)od) : 0.f;
    nd[i] = idg > 0 ? rsqrtf((float)idg) : 0.f;
  }
}

// ---- two-level exclusive scan of deg_in (chunk = 1024 = 256 thr x 4) ----
__global__ void scan_bsum(const int* __restrict__ deg, int* bsum, int n) {
  int tid = threadIdx.x;
  int base = blockIdx.x * 1024 + tid * 4;
  int s = 0;
  #pragma unroll
  for (int j = 0; j < 4; ++j) { int i = base + j; if (i < n) s += deg[i]; }
  int lane = tid & 63, wid = tid >> 6;
  #pragma unroll
  for (int off = 32; off > 0; off >>= 1) s += __shfl_down(s, off, 64);
  __shared__ int wtot[4];
  if (lane == 0) wtot[wid] = s;
  __syncthreads();
  if (tid == 0) bsum[blockIdx.x] = wtot[0] + wtot[1] + wtot[2] + wtot[3];
}

__global__ void scan_small(int* bsum, int nb, int* row_ptr, int n) {
  if (threadIdx.x == 0 && blockIdx.x == 0) {
    int acc = 0;
    for (int i = 0; i < nb; ++i) { int v = bsum[i]; bsum[i] = acc; acc += v; }
    row_ptr[n] = acc;
  }
}

__global__ void scan_chunks(const int* __restrict__ deg, const int* __restrict__ bsum,
                            int* row_ptr, int* cursor, int n) {
  int tid = threadIdx.x;
  int base = blockIdx.x * 1024 + tid * 4;
  int v0 = 0, v1 = 0, v2 = 0, v3 = 0;
  if (base + 0 < n) v0 = deg[base + 0];
  if (base + 1 < n) v1 = deg[base + 1];
  if (base + 2 < n) v2 = deg[base + 2];
  if (base + 3 < n) v3 = deg[base + 3];
  int s = v0 + v1 + v2 + v3;
  int lane = tid & 63, wid = tid >> 6;
  int incl = s;
  #pragma unroll
  for (int off = 1; off < 64; off <<= 1) {
    int t = __shfl_up(incl, off, 64);
    if (lane >= off) incl += t;
  }
  __shared__ int wtot[4];
  if (lane == 63) wtot[wid] = incl;
  __syncthreads();
  int woff = 0;
  for (int w = 0; w < wid; ++w) woff += wtot[w];
  int run = bsum[blockIdx.x] + woff + (incl - s);
  if (base + 0 < n) { row_ptr[base + 0] = run; cursor[base + 0] = run; } run += v0;
  if (base + 1 < n) { row_ptr[base + 1] = run; cursor[base + 1] = run; } run += v1;
  if (base + 2 < n) { row_ptr[base + 2] = run; cursor[base + 2] = run; } run += v2;
  if (base + 3 < n) { row_ptr[base + 3] = run; cursor[base + 3] = run; }
}

__global__ void fill_csr4(const int* __restrict__ src, const int* __restrict__ dst,
                          int* cursor, int* esrc, int e) {
  int i = (blockIdx.x * blockDim.x + threadIdx.x) * 4;
  if (i + 3 < e) {
    int4 s = *(const int4*)(src + i);
    int4 d = *(const int4*)(dst + i);
    int p0 = atomicAdd(&cursor[d.x], 1); esrc[p0] = s.x;
    int p1 = atomicAdd(&cursor[d.y], 1); esrc[p1] = s.y;
    int p2 = atomicAdd(&cursor[d.z], 1); esrc[p2] = s.z;
    int p3 = atomicAdd(&cursor[d.w], 1); esrc[p3] = s.w;
  } else {
    for (; i < e; ++i) {
      int pos = atomicAdd(&cursor[dst[i]], 1);
      esrc[pos] = src[i];
    }
  }
}

// ---- h = (x*ns) @ W ; 4 nodes per wave, lane = output feature ----
// W chunk-transposed in LDS as [K/4][F][4] so lane f reads its 4 weights of a
// k4-chunk as one conflict-free ds_read_b128. Node index forced wave-uniform
// (readfirstlane) so the 4 x-row loads scalarize to s_load_dwordx4.
// STRIDE-wide h rows; lanes f in [F, STRIDE) write 0 (padding for agg4).
template <int K, int F, int STRIDE>
__global__ __launch_bounds__(BLK) void gemm4(const float* __restrict__ x,
                                             const float* __restrict__ W,
                                             const float* __restrict__ ns,
                                             float* __restrict__ h, int n) {
  __shared__ float sW[K * F];
  for (int i = threadIdx.x; i < K * F; i += BLK) {
    int k = i / F, f = i - k * F;
    sW[(k >> 2) * (F * 4) + f * 4 + (k & 3)] = W[i];
  }
  __syncthreads();
  int f = threadIdx.x & 63;
  int fc = f < F ? f : 0;
  int node0 = (blockIdx.x * 4 + (threadIdx.x >> 6)) * 4;
  node0 = __builtin_amdgcn_readfirstlane(node0);
  if (node0 >= n) return;
  int i1 = min(node0 + 1, n - 1);
  int i2 = min(node0 + 2, n - 1);
  int i3 = min(node0 + 3, n - 1);
  const float* x0p = x + (size_t)node0 * K;
  const float* x1p = x + (size_t)i1 * K;
  const float* x2p = x + (size_t)i2 * K;
  const float* x3p = x + (size_t)i3 * K;
  float a0 = 0.f, a1 = 0.f, a2 = 0.f, a3 = 0.f;
  #pragma unroll
  for (int k4 = 0; k4 < K / 4; ++k4) {
    float4 w = *(const float4*)(sW + k4 * (F * 4) + fc * 4);
    float4 v0 = *(const float4*)(x0p + k4 * 4);
    float4 v1 = *(const float4*)(x1p + k4 * 4);
    float4 v2 = *(const float4*)(x2p + k4 * 4);
    float4 v3 = *(const float4*)(x3p + k4 * 4);
    a0 = fmaf(v0.x, w.x, a0); a0 = fmaf(v0.y, w.y, a0);
    a0 = fmaf(v0.z, w.z, a0); a0 = fmaf(v0.w, w.w, a0);
    a1 = fmaf(v1.x, w.x, a1); a1 = fmaf(v1.y, w.y, a1);
    a1 = fmaf(v1.z, w.z, a1); a1 = fmaf(v1.w, w.w, a1);
    a2 = fmaf(v2.x, w.x, a2); a2 = fmaf(v2.y, w.y, a2);
    a2 = fmaf(v2.z, w.z, a2); a2 = fmaf(v2.w, w.w, a2);
    a3 = fmaf(v3.x, w.x, a3); a3 = fmaf(v3.y, w.y, a3);
    a3 = fmaf(v3.z, w.z, a3); a3 = fmaf(v3.w, w.w, a3);
  }
  float s0 = ns[node0], s1 = ns[i1], s2 = ns[i2], s3 = ns[i3];
  if (f < STRIDE) {
    h[(size_t)node0 * STRIDE + f] = (f < F) ? a0 * s0 : 0.f;
    if (node0 + 1 < n) h[(size_t)i1 * STRIDE + f] = (f < F) ? a1 * s1 : 0.f;
    if (node0 + 2 < n) h[(size_t)i2 * STRIDE + f] = (f < F) ? a2 * s2 : 0.f;
    if (node0 + 3 < n) h[(size_t)i3 * STRIDE + f] = (f < F) ? a3 * s3 : 0.f;
  }
}

// ---- agg: 4 edges per wave-iteration; h rows are stride-64 fp32.
// group g = lane>>4 handles edge k+g; 16 lanes x float4 = 256B row.
template <bool RELU, int OUTF>
__global__ void agg4(const float* __restrict__ h, const int* __restrict__ row_ptr,
                     const int* __restrict__ esrc, const float* __restrict__ nd,
                     const float* __restrict__ b, float* __restrict__ out, int n) {
  int tid = threadIdx.x;
  int node = blockIdx.x * 4 + (tid >> 6);
  if (node >= n) return;
  int lane = tid & 63;
  int g = lane >> 4;
  int fl = lane & 15;
  int beg = row_ptr[node], end = row_ptr[node + 1];
  float ax = 0.f, ay = 0.f, az = 0.f, aw = 0.f;
  #pragma unroll 4
  for (int k = beg + g; k < end; k += 4) {
    int s = esrc[k];
    float4 v = *(const float4*)(h + (size_t)s * 64 + fl * 4);
    ax += v.x; ay += v.y; az += v.z; aw += v.w;
  }
  ax += __shfl_xor(ax, 16, 64); ay += __shfl_xor(ay, 16, 64);
  az += __shfl_xor(az, 16, 64); aw += __shfl_xor(aw, 16, 64);
  ax += __shfl_xor(ax, 32, 64); ay += __shfl_xor(ay, 32, 64);
  az += __shfl_xor(az, 32, 64); aw += __shfl_xor(aw, 32, 64);
  if (lane < OUTF / 4) {
    float ndv = nd[node];
    float4 bv = ((const float4*)b)[fl];
    float4 o;
    o.x = ax * ndv + bv.x;
    o.y = ay * ndv + bv.y;
    o.z = az * ndv + bv.z;
    o.w = aw * ndv + bv.w;
    if (RELU) {
      o.x = fmaxf(o.x, 0.f); o.y = fmaxf(o.y, 0.f);
      o.z = fmaxf(o.z, 0.f); o.w = fmaxf(o.w, 0.f);
    }
    *(float4*)(out + (size_t)node * OUTF + fl * 4) = o;
  }
}

extern "C" void kernel_launch(void* const* d_in, const int* in_sizes, int n_in,
                              void* d_out, int out_size, void* d_ws, size_t ws_size,
                              hipStream_t stream) {
  const float* features = (const float*)d_in[0];
  const int* src = (const int*)d_in[1];
  const int* dst = (const int*)d_in[2];
  const float* W0 = (const float*)d_in[3];
  const float* b0 = (const float*)d_in[4];
  const float* W1 = (const float*)d_in[5];
  const float* b1 = (const float*)d_in[6];
  const float* W2 = (const float*)d_in[7];
  const float* b2 = (const float*)d_in[8];
  const float* W3 = (const float*)d_in[9];
  const float* b3 = (const float*)d_in[10];

  const int n = in_sizes[0] / 128;  // 100000
  const int e = in_sizes[1];        // 1600000

  char* p = (char*)d_ws;
  auto alloc = [&](size_t bytes) {
    void* q = (void*)p;
    p += (bytes + 255) & ~(size_t)255;
    return q;
  };
  int* deg = (int*)alloc((size_t)2 * n * 4);
  float* ns = (float*)alloc((size_t)n * 4);
  float* nd = (float*)alloc((size_t)n * 4);
  int* row_ptr = (int*)alloc((size_t)(n + 1) * 4);
  int* cursor = (int*)alloc((size_t)n * 4);
  int* bsum = (int*)alloc(4096);
  int* esrc = (int*)alloc((size_t)e * 4);
  float* h = (float*)alloc((size_t)n * 64 * 4);
  float* xb = (float*)alloc((size_t)n * 64 * 4);

  int* deg_out = deg;
  int* deg_in = deg + n;
  const int nblk_scan = (n + 1023) / 1024;

  zero_int<<<(2 * n + BLK - 1) / BLK, BLK, 0, stream>>>(deg, 2 * n);
  count_deg4<<<((e + 3) / 4 + BLK - 1) / BLK, BLK, 0, stream>>>(src, dst, deg_out, deg_in, e);
  norms_k<<<(n + BLK - 1) / BLK, BLK, 0, stream>>>(deg_out, deg_in, ns, nd, n);
  scan_bsum<<<nblk_scan, BLK, 0, stream>>>(deg_in, bsum, n);
  scan_small<<<1, 64, 0, stream>>>(bsum, nblk_scan, row_ptr, n);
  scan_chunks<<<nblk_scan, BLK, 0, stream>>>(deg_in, bsum, row_ptr, cursor, n);
  fill_csr4<<<((e + 3) / 4 + BLK - 1) / BLK, BLK, 0, stream>>>(src, dst, cursor, esrc, e);

  const int gnode = (n + 3) / 4;        // agg: 4 nodes (waves) per block
  const int ggemm = (n + 15) / 16;      // gemm4: 16 nodes per block

  // layer 0: 128 -> 64, relu
  gemm4<128, 64, 64><<<ggemm, BLK, 0, stream>>>(features, W0, ns, h, n);
  agg4<true, 64><<<gnode, BLK, 0, stream>>>(h, row_ptr, esrc, nd, b0, xb, n);
  // layer 1: 64 -> 64, relu
  gemm4<64, 64, 64><<<ggemm, BLK, 0, stream>>>(xb, W1, ns, h, n);
  agg4<true, 64><<<gnode, BLK, 0, stream>>>(h, row_ptr, esrc, nd, b1, xb, n);
  // layer 2: 64 -> 64, relu
  gemm4<64, 64, 64><<<ggemm, BLK, 0, stream>>>(xb, W2, ns, h, n);
  agg4<true, 64><<<gnode, BLK, 0, stream>>>(h, row_ptr, esrc, nd, b2, xb, n);
  // layer 3: 64 -> 40, no relu (h padded to stride 64)
  gemm4<64, 40, 64><<<ggemm, BLK, 0, stream>>>(xb, W3, ns, h, n);
  agg4<false, 40><<<gnode, BLK, 0, stream>>>(h, row_ptr, esrc, nd, b3, (float*)d_out, n);
}

// Round 4
// 604.695 us; speedup vs baseline: 1.9623x; 1.2052x over previous
//
#include <hip/hip_runtime.h>

// GCN: 4x [h=(x*ns)@W ; agg=segment_sum(h[src],dst) ; out=agg*nd+b (+relu)]
// N=100000 nodes, E=1.6M edges, feats 128->64->64->64->40, fp32.
// R4: block-tiled gemm: 64 nodes/block, 256 thr, 4x4 register tile/thread,
//     x and W staged in LDS per 64-wide k-tile (padded, conflict-free b128).

constexpr int BLK = 256;

__global__ void zero_int(int* p, int n) {
  int i = blockIdx.x * blockDim.x + threadIdx.x;
  if (i < n) p[i] = 0;
}

__global__ void count_deg4(const int* __restrict__ src, const int* __restrict__ dst,
                           int* deg_out, int* deg_in, int e) {
  int i = (blockIdx.x * blockDim.x + threadIdx.x) * 4;
  if (i + 3 < e) {
    int4 s = *(const int4*)(src + i);
    int4 d = *(const int4*)(dst + i);
    atomicAdd(&deg_out[s.x], 1); atomicAdd(&deg_out[s.y], 1);
    atomicAdd(&deg_out[s.z], 1); atomicAdd(&deg_out[s.w], 1);
    atomicAdd(&deg_in[d.x], 1); atomicAdd(&deg_in[d.y], 1);
    atomicAdd(&deg_in[d.z], 1); atomicAdd(&deg_in[d.w], 1);
  } else {
    for (; i < e; ++i) {
      atomicAdd(&deg_out[src[i]], 1);
      atomicAdd(&deg_in[dst[i]], 1);
    }
  }
}

__global__ void norms_k(const int* __restrict__ deg_out, const int* __restrict__ deg_in,
                        float* ns, float* nd, int n) {
  int i = blockIdx.x * blockDim.x + threadIdx.x;
  if (i < n) {
    int od = deg_out[i], idg = deg_in[i];
    ns[i] = od > 0 ? rsqrtf((float)od) : 0.f;
    nd[i] = idg > 0 ? rsqrtf((float)idg) : 0.f;
  }
}

// ---- two-level exclusive scan of deg_in (chunk = 1024 = 256 thr x 4) ----
__global__ void scan_bsum(const int* __restrict__ deg, int* bsum, int n) {
  int tid = threadIdx.x;
  int base = blockIdx.x * 1024 + tid * 4;
  int s = 0;
  #pragma unroll
  for (int j = 0; j < 4; ++j) { int i = base + j; if (i < n) s += deg[i]; }
  int lane = tid & 63, wid = tid >> 6;
  #pragma unroll
  for (int off = 32; off > 0; off >>= 1) s += __shfl_down(s, off, 64);
  __shared__ int wtot[4];
  if (lane == 0) wtot[wid] = s;
  __syncthreads();
  if (tid == 0) bsum[blockIdx.x] = wtot[0] + wtot[1] + wtot[2] + wtot[3];
}

__global__ void scan_small(int* bsum, int nb, int* row_ptr, int n) {
  if (threadIdx.x == 0 && blockIdx.x == 0) {
    int acc = 0;
    for (int i = 0; i < nb; ++i) { int v = bsum[i]; bsum[i] = acc; acc += v; }
    row_ptr[n] = acc;
  }
}

__global__ void scan_chunks(const int* __restrict__ deg, const int* __restrict__ bsum,
                            int* row_ptr, int* cursor, int n) {
  int tid = threadIdx.x;
  int base = blockIdx.x * 1024 + tid * 4;
  int v0 = 0, v1 = 0, v2 = 0, v3 = 0;
  if (base + 0 < n) v0 = deg[base + 0];
  if (base + 1 < n) v1 = deg[base + 1];
  if (base + 2 < n) v2 = deg[base + 2];
  if (base + 3 < n) v3 = deg[base + 3];
  int s = v0 + v1 + v2 + v3;
  int lane = tid & 63, wid = tid >> 6;
  int incl = s;
  #pragma unroll
  for (int off = 1; off < 64; off <<= 1) {
    int t = __shfl_up(incl, off, 64);
    if (lane >= off) incl += t;
  }
  __shared__ int wtot[4];
  if (lane == 63) wtot[wid] = incl;
  __syncthreads();
  int woff = 0;
  for (int w = 0; w < wid; ++w) woff += wtot[w];
  int run = bsum[blockIdx.x] + woff + (incl - s);
  if (base + 0 < n) { row_ptr[base + 0] = run; cursor[base + 0] = run; } run += v0;
  if (base + 1 < n) { row_ptr[base + 1] = run; cursor[base + 1] = run; } run += v1;
  if (base + 2 < n) { row_ptr[base + 2] = run; cursor[base + 2] = run; } run += v2;
  if (base + 3 < n) { row_ptr[base + 3] = run; cursor[base + 3] = run; }
}

__global__ void fill_csr4(const int* __restrict__ src, const int* __restrict__ dst,
                          int* cursor, int* esrc, int e) {
  int i = (blockIdx.x * blockDim.x + threadIdx.x) * 4;
  if (i + 3 < e) {
    int4 s = *(const int4*)(src + i);
    int4 d = *(const int4*)(dst + i);
    int p0 = atomicAdd(&cursor[d.x], 1); esrc[p0] = s.x;
    int p1 = atomicAdd(&cursor[d.y], 1); esrc[p1] = s.y;
    int p2 = atomicAdd(&cursor[d.z], 1); esrc[p2] = s.z;
    int p3 = atomicAdd(&cursor[d.w], 1); esrc[p3] = s.w;
  } else {
    for (; i < e; ++i) {
      int pos = atomicAdd(&cursor[dst[i]], 1);
      esrc[pos] = src[i];
    }
  }
}

// ---- h = (x*ns) @ W ; block-tiled GEMM ----
// 64 nodes/block, 256 threads; thread (ft=t&15, nt=t>>4) owns nodes 4nt..4nt+3
// x feats 4ft..4ft+3 (16 fp32 accumulators). Per 64-wide k-tile: stage
// sx[64][68] (pad 4 keeps 16B align; column b128 reads 2-way = free) and
// sW[64][F] (linear copy of W rows). Inner k4: 8 ds_read_b128 + 64 FMA.
// STRIDE-wide h rows; feats in [F, STRIDE) write 0 (padding for agg4).
template <int K, int F, int STRIDE>
__global__ __launch_bounds__(BLK) void gemm_tile(const float* __restrict__ x,
                                                 const float* __restrict__ W,
                                                 const float* __restrict__ ns,
                                                 float* __restrict__ h, int n) {
  constexpr int KT = 64;       // k-tile
  constexpr int KP = KT + 4;   // padded LDS row (272B, 16B-aligned)
  __shared__ float sx[64 * KP];
  __shared__ float sW[KT * F];
  const int tid = threadIdx.x;
  const int n0 = blockIdx.x * 64;
  const int ft = tid & 15, nt = tid >> 4;
  const int fbase = (4 * ft < F) ? 4 * ft : 0;
  float acc[4][4] = {};

  for (int kt = 0; kt < K; kt += KT) {
    if (kt) __syncthreads();
    // stage W k-chunk (rows kt..kt+63 are contiguous in row-major [K][F])
    for (int i = tid; i < KT * F; i += BLK) sW[i] = W[kt * F + i];
    // stage x k-chunk: 64 nodes x 16 float4
    for (int idx = tid; idx < 64 * (KT / 4); idx += BLK) {
      int node = idx >> 4;
      int kk = idx & 15;
      int gn = min(n0 + node, n - 1);
      float4 v = *(const float4*)(x + (size_t)gn * K + kt + kk * 4);
      *(float4*)(sx + node * KP + kk * 4) = v;
    }
    __syncthreads();

    #pragma unroll 4
    for (int k0 = 0; k0 < KT; k0 += 4) {
      float4 xv0 = *(const float4*)(sx + (4 * nt + 0) * KP + k0);
      float4 xv1 = *(const float4*)(sx + (4 * nt + 1) * KP + k0);
      float4 xv2 = *(const float4*)(sx + (4 * nt + 2) * KP + k0);
      float4 xv3 = *(const float4*)(sx + (4 * nt + 3) * KP + k0);
      float4 w0 = *(const float4*)(sW + (k0 + 0) * F + fbase);
      float4 w1 = *(const float4*)(sW + (k0 + 1) * F + fbase);
      float4 w2 = *(const float4*)(sW + (k0 + 2) * F + fbase);
      float4 w3 = *(const float4*)(sW + (k0 + 3) * F + fbase);
#define GCN_STEP(C, WV)                                                  \
      acc[0][0] = fmaf(xv0.C, WV.x, acc[0][0]);                          \
      acc[0][1] = fmaf(xv0.C, WV.y, acc[0][1]);                          \
      acc[0][2] = fmaf(xv0.C, WV.z, acc[0][2]);                          \
      acc[0][3] = fmaf(xv0.C, WV.w, acc[0][3]);                          \
      acc[1][0] = fmaf(xv1.C, WV.x, acc[1][0]);                          \
      acc[1][1] = fmaf(xv1.C, WV.y, acc[1][1]);                          \
      acc[1][2] = fmaf(xv1.C, WV.z, acc[1][2]);                          \
      acc[1][3] = fmaf(xv1.C, WV.w, acc[1][3]);                          \
      acc[2][0] = fmaf(xv2.C, WV.x, acc[2][0]);                          \
      acc[2][1] = fmaf(xv2.C, WV.y, acc[2][1]);                          \
      acc[2][2] = fmaf(xv2.C, WV.z, acc[2][2]);                          \
      acc[2][3] = fmaf(xv2.C, WV.w, acc[2][3]);                          \
      acc[3][0] = fmaf(xv3.C, WV.x, acc[3][0]);                          \
      acc[3][1] = fmaf(xv3.C, WV.y, acc[3][1]);                          \
      acc[3][2] = fmaf(xv3.C, WV.z, acc[3][2]);                          \
      acc[3][3] = fmaf(xv3.C, WV.w, acc[3][3]);
      GCN_STEP(x, w0)
      GCN_STEP(y, w1)
      GCN_STEP(z, w2)
      GCN_STEP(w, w3)
#undef GCN_STEP
    }
  }

  #pragma unroll
  for (int i = 0; i < 4; ++i) {
    int node = n0 + 4 * nt + i;
    if (node < n) {
      float s = ns[node];
      float4 o;
      if (4 * ft < F) {
        o.x = acc[i][0] * s; o.y = acc[i][1] * s;
        o.z = acc[i][2] * s; o.w = acc[i][3] * s;
      } else {
        o.x = o.y = o.z = o.w = 0.f;
      }
      *(float4*)(h + (size_t)node * STRIDE + 4 * ft) = o;
    }
  }
}

// ---- agg: 4 edges per wave-iteration; h rows are stride-64 fp32.
// group g = lane>>4 handles edge k+g; 16 lanes x float4 = 256B row.
template <bool RELU, int OUTF>
__global__ void agg4(const float* __restrict__ h, const int* __restrict__ row_ptr,
                     const int* __restrict__ esrc, const float* __restrict__ nd,
                     const float* __restrict__ b, float* __restrict__ out, int n) {
  int tid = threadIdx.x;
  int node = blockIdx.x * 4 + (tid >> 6);
  if (node >= n) return;
  int lane = tid & 63;
  int g = lane >> 4;
  int fl = lane & 15;
  int beg = row_ptr[node], end = row_ptr[node + 1];
  float ax = 0.f, ay = 0.f, az = 0.f, aw = 0.f;
  #pragma unroll 4
  for (int k = beg + g; k < end; k += 4) {
    int s = esrc[k];
    float4 v = *(const float4*)(h + (size_t)s * 64 + fl * 4);
    ax += v.x; ay += v.y; az += v.z; aw += v.w;
  }
  ax += __shfl_xor(ax, 16, 64); ay += __shfl_xor(ay, 16, 64);
  az += __shfl_xor(az, 16, 64); aw += __shfl_xor(aw, 16, 64);
  ax += __shfl_xor(ax, 32, 64); ay += __shfl_xor(ay, 32, 64);
  az += __shfl_xor(az, 32, 64); aw += __shfl_xor(aw, 32, 64);
  if (lane < OUTF / 4) {
    float ndv = nd[node];
    float4 bv = ((const float4*)b)[fl];
    float4 o;
    o.x = ax * ndv + bv.x;
    o.y = ay * ndv + bv.y;
    o.z = az * ndv + bv.z;
    o.w = aw * ndv + bv.w;
    if (RELU) {
      o.x = fmaxf(o.x, 0.f); o.y = fmaxf(o.y, 0.f);
      o.z = fmaxf(o.z, 0.f); o.w = fmaxf(o.w, 0.f);
    }
    *(float4*)(out + (size_t)node * OUTF + fl * 4) = o;
  }
}

extern "C" void kernel_launch(void* const* d_in, const int* in_sizes, int n_in,
                              void* d_out, int out_size, void* d_ws, size_t ws_size,
                              hipStream_t stream) {
  const float* features = (const float*)d_in[0];
  const int* src = (const int*)d_in[1];
  const int* dst = (const int*)d_in[2];
  const float* W0 = (const float*)d_in[3];
  const float* b0 = (const float*)d_in[4];
  const float* W1 = (const float*)d_in[5];
  const float* b1 = (const float*)d_in[6];
  const float* W2 = (const float*)d_in[7];
  const float* b2 = (const float*)d_in[8];
  const float* W3 = (const float*)d_in[9];
  const float* b3 = (const float*)d_in[10];

  const int n = in_sizes[0] / 128;  // 100000
  const int e = in_sizes[1];        // 1600000

  char* p = (char*)d_ws;
  auto alloc = [&](size_t bytes) {
    void* q = (void*)p;
    p += (bytes + 255) & ~(size_t)255;
    return q;
  };
  int* deg = (int*)alloc((size_t)2 * n * 4);
  float* ns = (float*)alloc((size_t)n * 4);
  float* nd = (float*)alloc((size_t)n * 4);
  int* row_ptr = (int*)alloc((size_t)(n + 1) * 4);
  int* cursor = (int*)alloc((size_t)n * 4);
  int* bsum = (int*)alloc(4096);
  int* esrc = (int*)alloc((size_t)e * 4);
  float* h = (float*)alloc((size_t)n * 64 * 4);
  float* xb = (float*)alloc((size_t)n * 64 * 4);

  int* deg_out = deg;
  int* deg_in = deg + n;
  const int nblk_scan = (n + 1023) / 1024;

  zero_int<<<(2 * n + BLK - 1) / BLK, BLK, 0, stream>>>(deg, 2 * n);
  count_deg4<<<((e + 3) / 4 + BLK - 1) / BLK, BLK, 0, stream>>>(src, dst, deg_out, deg_in, e);
  norms_k<<<(n + BLK - 1) / BLK, BLK, 0, stream>>>(deg_out, deg_in, ns, nd, n);
  scan_bsum<<<nblk_scan, BLK, 0, stream>>>(deg_in, bsum, n);
  scan_small<<<1, 64, 0, stream>>>(bsum, nblk_scan, row_ptr, n);
  scan_chunks<<<nblk_scan, BLK, 0, stream>>>(deg_in, bsum, row_ptr, cursor, n);
  fill_csr4<<<((e + 3) / 4 + BLK - 1) / BLK, BLK, 0, stream>>>(src, dst, cursor, esrc, e);

  const int gnode = (n + 3) / 4;   // agg: 4 nodes (waves) per block
  const int gblk = (n + 63) / 64;  // gemm_tile: 64 nodes per block

  // layer 0: 128 -> 64, relu
  gemm_tile<128, 64, 64><<<gblk, BLK, 0, stream>>>(features, W0, ns, h, n);
  agg4<true, 64><<<gnode, BLK, 0, stream>>>(h, row_ptr, esrc, nd, b0, xb, n);
  // layer 1: 64 -> 64, relu
  gemm_tile<64, 64, 64><<<gblk, BLK, 0, stream>>>(xb, W1, ns, h, n);
  agg4<true, 64><<<gnode, BLK, 0, stream>>>(h, row_ptr, esrc, nd, b1, xb, n);
  // layer 2: 64 -> 64, relu
  gemm_tile<64, 64, 64><<<gblk, BLK, 0, stream>>>(xb, W2, ns, h, n);
  agg4<true, 64><<<gnode, BLK, 0, stream>>>(h, row_ptr, esrc, nd, b2, xb, n);
  // layer 3: 64 -> 40, no relu (h padded to stride 64)
  gemm_tile<64, 40, 64><<<gblk, BLK, 0, stream>>>(xb, W3, ns, h, n);
  agg4<false, 40><<<gnode, BLK, 0, stream>>>(h, row_ptr, esrc, nd, b3, (float*)d_out, n);
}